// Round 2
// baseline (203.125 us; speedup 1.0000x reference)
//
#include <hip/hip_runtime.h>

// CovarianceLayer: out = boxmean5x5( (center(x)-boxmean5x5(x)) * (center(y)-boxmean5x5(y)) )
// x,y: [16,1,1024,1024] fp32; out: [16,1,1016,1016] fp32.
//
// Register-resident vertical-scan formulation (no LDS, no __syncthreads):
//  - each WAVE owns a 256-input-column strip (lane k -> float4 at col base+4k),
//    slides down a 16-output-row chunk (24 input rows incl. 8 priming rows).
//  - vertical 5-row box sums vx,vy,vp held as running sums + 5-deep float4 ring
//    buffers (static indices via full unroll of the 24-step loop).
//  - horizontal 5-sums via __shfl_up/__shfl_down of neighbor-lane edge elements.
//  - explicit 1-row software prefetch: x/y loads for step s+1 are issued at the
//    top of step s, so HBM/L3 latency hides under the current step's
//    shfl+VALU chain (r0 version was latency-bound: VALUBusy 11%,
//    HBM 23%, occupancy 24%).
//  - RCHUNK 32->16 doubles the grid to 5120 waves (~5/SIMD) for latency
//    hiding; costs 1.5x (vs 1.25x) vertical read amplification, absorbed
//    by L2/L3 (inputs fully L3-resident).
//  - __launch_bounds__(256,4): cap 128 VGPR so the 15x float4 ring +
//    prefetch regs live honestly in registers (default alloc squeezed to
//    64 VGPR -> rematerialized reloads on the critical path).
//  - nontemporal output stores via native ext_vector_type (the HIP
//    float4 class pointer is rejected by __builtin_nontemporal_store).
// Valid outputs per 256-col wave strip: 248 cols (lanes 1..62). 5 strips cover
// 1016. Edge lanes' shfl out-of-range returns own value (finite) -> garbage
// only ever flows into masked-off outputs.

#define W 1024
#define H 1024
#define OW 1016
#define OH 1016
#define NBATCH 16
#define NSTRIP 5
#define NCHUNK 64
#define RCHUNK 16
#define NSTEP (RCHUNK + 8)    // 24 input rows per job
#define STRIP_OUT 248

typedef float floatx4 __attribute__((ext_vector_type(4)));

__device__ __forceinline__ float shfl_up1(float v) { return __shfl_up(v, 1, 64); }
__device__ __forceinline__ float shfl_dn1(float v) { return __shfl_down(v, 1, 64); }

__global__ __launch_bounds__(256, 4) void cov_kernel(
    const float* __restrict__ x, const float* __restrict__ y,
    float* __restrict__ out)
{
    const int wid  = (blockIdx.x << 2) + (threadIdx.x >> 6);
    const int lane = threadIdx.x & 63;

    // job decode: chunk fastest (adjacent waves share row halo in L2)
    const int chunk = wid & (NCHUNK - 1);
    const int rest  = wid >> 6;
    const int strip = rest % NSTRIP;
    const int batch = rest / NSTRIP;

    const int o0   = chunk * RCHUNK;      // first output row of this job
    const int base = strip * STRIP_OUT;   // first input col of this strip

    int col4 = base + (lane << 2);
    if (col4 > W - 4) col4 = W - 4;       // clamp (strip 4 tail lanes; masked below)

    const float* __restrict__ xb = x + (size_t)batch * H * W;
    const float* __restrict__ yb = y + (size_t)batch * H * W;
    float* __restrict__ ob = out + (size_t)batch * OH * OW;

    const int j4 = base + ((lane - 1) << 2);   // first output col this lane stores
    const bool lane_ok = (lane >= 1) && (lane <= 62) && (j4 <= OW - 4);

    constexpr float inv25 = 1.0f / 25.0f;

    float4 xr[5], yr[5], pr[5];
    float4 vx = make_float4(0.f, 0.f, 0.f, 0.f);
    float4 vy = vx, vp = vx;
    #pragma unroll
    for (int u = 0; u < 5; ++u) { xr[u] = vx; yr[u] = vx; pr[u] = vx; }

    // software prefetch: row 0 in flight before the loop
    float4 xn_n, yn_n;
    {
        int r = o0; if (r > H - 1) r = H - 1;
        const int off = r * W + col4;
        xn_n = *(const float4*)(xb + off);
        yn_n = *(const float4*)(yb + off);
    }

    #pragma unroll
    for (int s = 0; s < NSTEP; ++s) {
        const int u = s % 5;               // compile-time after full unroll
        const float4 xn = xn_n;
        const float4 yn = yn_n;

        // issue next row's loads NOW; consumed next iteration (latency hidden
        // under this step's shfl+VALU chain)
        if (s + 1 < NSTEP) {
            int rn = o0 + s + 1; if (rn > H - 1) rn = H - 1;
            const int offn = rn * W + col4;
            xn_n = *(const float4*)(xb + offn);
            yn_n = *(const float4*)(yb + offn);
        }

        // vertical running 5-sums (rows s-4..s), ring replaces row s-5
        vx.x += xn.x - xr[u].x; vx.y += xn.y - xr[u].y;
        vx.z += xn.z - xr[u].z; vx.w += xn.w - xr[u].w;
        vy.x += yn.x - yr[u].x; vy.y += yn.y - yr[u].y;
        vy.z += yn.z - yr[u].z; vy.w += yn.w - yr[u].w;
        xr[u] = xn; yr[u] = yn;

        // horizontal 5-sums at this lane's 4 cols (neighbors via shfl)
        const float vxl0 = shfl_up1(vx.z), vxl1 = shfl_up1(vx.w);
        const float vxr0 = shfl_dn1(vx.x), vxr1 = shfl_dn1(vx.y);
        const float vyl0 = shfl_up1(vy.z), vyl1 = shfl_up1(vy.w);
        const float vyr0 = shfl_dn1(vy.x), vyr1 = shfl_dn1(vy.y);

        const float hx0 = vxl0 + vxl1 + vx.x + vx.y + vx.z;
        const float hx1 = hx0 - vxl0 + vx.w;
        const float hx2 = hx1 - vxl1 + vxr0;
        const float hx3 = hx2 - vx.x + vxr1;
        const float hy0 = vyl0 + vyl1 + vy.x + vy.y + vy.z;
        const float hy1 = hy0 - vyl0 + vy.w;
        const float hy2 = hy1 - vyl1 + vyr0;
        const float hy3 = hy2 - vy.x + vyr1;

        // centers: row r-2 = ring slot (u+3)%5
        const float4 cx4 = xr[(u + 3) % 5];
        const float4 cy4 = yr[(u + 3) % 5];

        float4 p;
        p.x = (cx4.x - hx0 * inv25) * (cy4.x - hy0 * inv25);
        p.y = (cx4.y - hx1 * inv25) * (cy4.y - hy1 * inv25);
        p.z = (cx4.z - hx2 * inv25) * (cy4.z - hy2 * inv25);
        p.w = (cx4.w - hx3 * inv25) * (cy4.w - hy3 * inv25);

        // vertical running 5-sum of p
        vp.x += p.x - pr[u].x; vp.y += p.y - pr[u].y;
        vp.z += p.z - pr[u].z; vp.w += p.w - pr[u].w;
        pr[u] = p;

        const int i = o0 + s - 8;          // output row
        if (s >= 8 && i < OH) {            // wave-uniform condition
            const float vpl0 = shfl_up1(vp.z), vpl1 = shfl_up1(vp.w);
            const float vpr0 = shfl_dn1(vp.x), vpr1 = shfl_dn1(vp.y);
            const float h0 = vpl0 + vpl1 + vp.x + vp.y + vp.z;
            const float h1 = h0 - vpl0 + vp.w;
            const float h2 = h1 - vpl1 + vpr0;
            const float h3 = h2 - vp.x + vpr1;
            if (lane_ok) {
                floatx4 o4 = { h0 * inv25, h1 * inv25, h2 * inv25, h3 * inv25 };
                __builtin_nontemporal_store(o4, (floatx4*)(ob + (size_t)i * OW + j4));
            }
        }
    }
}

extern "C" void kernel_launch(void* const* d_in, const int* in_sizes, int n_in,
                              void* d_out, int out_size, void* d_ws, size_t ws_size,
                              hipStream_t stream) {
    const float* x = (const float*)d_in[0];
    const float* y = (const float*)d_in[1];
    // d_in[2]/d_in[3]: constant conv masks (1/25 box, center impulse) — baked in.
    float* out = (float*)d_out;

    // 16 batch x 5 strips x 64 row-chunks = 5120 wave-jobs = 1280 blocks x 4 waves
    dim3 grid(NBATCH * NSTRIP * NCHUNK / 4);
    dim3 block(256);
    hipLaunchKernelGGL(cov_kernel, grid, block, 0, stream, x, y, out);
}

// Round 3
// 197.433 us; speedup vs baseline: 1.0288x; 1.0288x over previous
//
#include <hip/hip_runtime.h>

// CovarianceLayer: out = boxmean5x5( (center(x)-boxmean5x5(x)) * (center(y)-boxmean5x5(y)) )
// x,y: [16,1,1024,1024] fp32; out: [16,1,1016,1016] fp32.
//
// Register-resident vertical-scan formulation (no LDS, no __syncthreads):
//  - each WAVE owns a 256-input-column strip (lane k -> float4 at col base+4k),
//    slides down a 16-output-row chunk (24 input rows incl. 8 priming rows).
//  - vertical 5-row box sums vx,vy,vp held as running sums + 5-deep float4 ring
//    buffers (static indices via full unroll of the 24-step loop).
//  - horizontal 5-sums via __shfl_up/__shfl_down of neighbor-lane edge elements.
//  - explicit 1-row software prefetch: x/y loads for step s+1 issued at the top
//    of step s.
//
// r2 post-mortem: VGPR_Count=64 while live state is ~90 VGPRs (3 rings x 5 x
// float4 + vx/vy/vp + prefetch) -> allocator squeezed for 8 waves/EU and
// spilled ring slots to scratch; per-SIMD step cost ~1850cy invariant to
// occupancy (r0 vs r2), VALUBusy 15%, HBM 23% -> scratch-latency-bound.
// Fix: amdgpu_waves_per_eu(4,4) pins the occupancy target so the allocator
// budgets 128 VGPR and keeps the rings in registers. Geometry unchanged from
// r2 to isolate this one variable.
//
// Valid outputs per 256-col wave strip: 248 cols (lanes 1..62). 5 strips cover
// 1016. Edge lanes' shfl out-of-range returns own value (finite) -> garbage
// only ever flows into masked-off outputs.

#define W 1024
#define H 1024
#define OW 1016
#define OH 1016
#define NBATCH 16
#define NSTRIP 5
#define NCHUNK 64
#define RCHUNK 16
#define NSTEP (RCHUNK + 8)    // 24 input rows per job
#define STRIP_OUT 248

typedef float floatx4 __attribute__((ext_vector_type(4)));

__device__ __forceinline__ float shfl_up1(float v) { return __shfl_up(v, 1, 64); }
__device__ __forceinline__ float shfl_dn1(float v) { return __shfl_down(v, 1, 64); }

__global__ __launch_bounds__(256)
__attribute__((amdgpu_waves_per_eu(4, 4)))
void cov_kernel(
    const float* __restrict__ x, const float* __restrict__ y,
    float* __restrict__ out)
{
    const int wid  = (blockIdx.x << 2) + (threadIdx.x >> 6);
    const int lane = threadIdx.x & 63;

    // job decode: chunk fastest (adjacent waves share row halo in L2)
    const int chunk = wid & (NCHUNK - 1);
    const int rest  = wid >> 6;
    const int strip = rest % NSTRIP;
    const int batch = rest / NSTRIP;

    const int o0   = chunk * RCHUNK;      // first output row of this job
    const int base = strip * STRIP_OUT;   // first input col of this strip

    int col4 = base + (lane << 2);
    if (col4 > W - 4) col4 = W - 4;       // clamp (strip 4 tail lanes; masked below)

    const float* __restrict__ xb = x + (size_t)batch * H * W;
    const float* __restrict__ yb = y + (size_t)batch * H * W;
    float* __restrict__ ob = out + (size_t)batch * OH * OW;

    const int j4 = base + ((lane - 1) << 2);   // first output col this lane stores
    const bool lane_ok = (lane >= 1) && (lane <= 62) && (j4 <= OW - 4);

    constexpr float inv25 = 1.0f / 25.0f;

    float4 xr[5], yr[5], pr[5];
    float4 vx = make_float4(0.f, 0.f, 0.f, 0.f);
    float4 vy = vx, vp = vx;
    #pragma unroll
    for (int u = 0; u < 5; ++u) { xr[u] = vx; yr[u] = vx; pr[u] = vx; }

    // software prefetch: row 0 in flight before the loop
    float4 xn_n, yn_n;
    {
        int r = o0; if (r > H - 1) r = H - 1;
        const int off = r * W + col4;
        xn_n = *(const float4*)(xb + off);
        yn_n = *(const float4*)(yb + off);
    }

    #pragma unroll
    for (int s = 0; s < NSTEP; ++s) {
        const int u = s % 5;               // compile-time after full unroll
        const float4 xn = xn_n;
        const float4 yn = yn_n;

        // issue next row's loads NOW; consumed next iteration (latency hidden
        // under this step's shfl+VALU chain)
        if (s + 1 < NSTEP) {
            int rn = o0 + s + 1; if (rn > H - 1) rn = H - 1;
            const int offn = rn * W + col4;
            xn_n = *(const float4*)(xb + offn);
            yn_n = *(const float4*)(yb + offn);
        }

        // vertical running 5-sums (rows s-4..s), ring replaces row s-5
        vx.x += xn.x - xr[u].x; vx.y += xn.y - xr[u].y;
        vx.z += xn.z - xr[u].z; vx.w += xn.w - xr[u].w;
        vy.x += yn.x - yr[u].x; vy.y += yn.y - yr[u].y;
        vy.z += yn.z - yr[u].z; vy.w += yn.w - yr[u].w;
        xr[u] = xn; yr[u] = yn;

        // horizontal 5-sums at this lane's 4 cols (neighbors via shfl)
        const float vxl0 = shfl_up1(vx.z), vxl1 = shfl_up1(vx.w);
        const float vxr0 = shfl_dn1(vx.x), vxr1 = shfl_dn1(vx.y);
        const float vyl0 = shfl_up1(vy.z), vyl1 = shfl_up1(vy.w);
        const float vyr0 = shfl_dn1(vy.x), vyr1 = shfl_dn1(vy.y);

        const float hx0 = vxl0 + vxl1 + vx.x + vx.y + vx.z;
        const float hx1 = hx0 - vxl0 + vx.w;
        const float hx2 = hx1 - vxl1 + vxr0;
        const float hx3 = hx2 - vx.x + vxr1;
        const float hy0 = vyl0 + vyl1 + vy.x + vy.y + vy.z;
        const float hy1 = hy0 - vyl0 + vy.w;
        const float hy2 = hy1 - vyl1 + vyr0;
        const float hy3 = hy2 - vy.x + vyr1;

        // centers: row r-2 = ring slot (u+3)%5
        const float4 cx4 = xr[(u + 3) % 5];
        const float4 cy4 = yr[(u + 3) % 5];

        float4 p;
        p.x = (cx4.x - hx0 * inv25) * (cy4.x - hy0 * inv25);
        p.y = (cx4.y - hx1 * inv25) * (cy4.y - hy1 * inv25);
        p.z = (cx4.z - hx2 * inv25) * (cy4.z - hy2 * inv25);
        p.w = (cx4.w - hx3 * inv25) * (cy4.w - hy3 * inv25);

        // vertical running 5-sum of p
        vp.x += p.x - pr[u].x; vp.y += p.y - pr[u].y;
        vp.z += p.z - pr[u].z; vp.w += p.w - pr[u].w;
        pr[u] = p;

        const int i = o0 + s - 8;          // output row
        if (s >= 8 && i < OH) {            // wave-uniform condition
            const float vpl0 = shfl_up1(vp.z), vpl1 = shfl_up1(vp.w);
            const float vpr0 = shfl_dn1(vp.x), vpr1 = shfl_dn1(vp.y);
            const float h0 = vpl0 + vpl1 + vp.x + vp.y + vp.z;
            const float h1 = h0 - vpl0 + vp.w;
            const float h2 = h1 - vpl1 + vpr0;
            const float h3 = h2 - vp.x + vpr1;
            if (lane_ok) {
                floatx4 o4 = { h0 * inv25, h1 * inv25, h2 * inv25, h3 * inv25 };
                __builtin_nontemporal_store(o4, (floatx4*)(ob + (size_t)i * OW + j4));
            }
        }
    }
}

extern "C" void kernel_launch(void* const* d_in, const int* in_sizes, int n_in,
                              void* d_out, int out_size, void* d_ws, size_t ws_size,
                              hipStream_t stream) {
    const float* x = (const float*)d_in[0];
    const float* y = (const float*)d_in[1];
    // d_in[2]/d_in[3]: constant conv masks (1/25 box, center impulse) — baked in.
    float* out = (float*)d_out;

    // 16 batch x 5 strips x 64 row-chunks = 5120 wave-jobs = 1280 blocks x 4 waves
    dim3 grid(NBATCH * NSTRIP * NCHUNK / 4);
    dim3 block(256);
    hipLaunchKernelGGL(cov_kernel, grid, block, 0, stream, x, y, out);
}

// Round 4
// 195.922 us; speedup vs baseline: 1.0368x; 1.0077x over previous
//
#include <hip/hip_runtime.h>

// CovarianceLayer: out = boxmean5x5( (center(x)-boxmean5x5(x)) * (center(y)-boxmean5x5(y)) )
// x,y: [16,1,1024,1024] fp32; out: [16,1,1016,1016] fp32.
//
// r3 post-mortem: allocator pinned at 64 VGPR (ignored waves_per_eu(4,4));
// with ~90 live floats (3 reg-rings) it rematerializes x/y ring slots as
// just-in-time global reloads and spills the p-ring to scratch -> per-wave
// step cost ~8900 cy (213k cy / 24 steps, all waves resident), ~20x the
// VALU+shfl chain model. Occupancy-invariant (r0 vs r3) because every wave
// sits in s_waitcnt on its own serialized reloads.
//
// r4: remove the register demand structurally so 64 VGPRs truly suffice:
//  - p-ring (the un-rematerializable, forced-spill state) -> per-wave LDS
//    ring, 5 rows x 256 floats = 5 KB/wave, 20 KB/block. No __syncthreads
//    (each wave touches only its own ring); ds_read/write_b128 conflict-free.
//  - x/y reg-rings deleted. Vertical running 5-sums subtract x[r-5],y[r-5]
//    re-loaded from global (L2-hit; prefetched 1 step ahead = controlled
//    version of the remat the compiler was doing un-prefetched).
//  - center row r-2 via 2-deep delay registers (16 VGPRs).
//  - rolled loop (#pragma unroll 1) + 1-ahead prefetch of all 4 streamed
//    loads; LDS ring slot via wrap counter (no %5).
// Live state ~55 floats. Geometry unchanged from r2/r3 (RCHUNK=16, 5120
// waves, 5/SIMD) to isolate the structural change.
//
// Valid outputs per 256-col wave strip: 248 cols (lanes 1..62). 5 strips
// cover 1016. Edge lanes' shfl out-of-range returns own value (finite) ->
// garbage only ever flows into masked-off outputs.

#define W 1024
#define H 1024
#define OW 1016
#define OH 1016
#define NBATCH 16
#define NSTRIP 5
#define NCHUNK 64
#define RCHUNK 16
#define NSTEP (RCHUNK + 8)    // 24 input rows per job
#define STRIP_OUT 248

typedef float floatx4 __attribute__((ext_vector_type(4)));

__device__ __forceinline__ float shfl_up1(float v) { return __shfl_up(v, 1, 64); }
__device__ __forceinline__ float shfl_dn1(float v) { return __shfl_down(v, 1, 64); }

__global__ __launch_bounds__(256) void cov_kernel(
    const float* __restrict__ x, const float* __restrict__ y,
    float* __restrict__ out)
{
    // per-wave p-ring: [wave][slot][lane] float4
    __shared__ float4 pring[4 * 5 * 64];

    const int wid  = (blockIdx.x << 2) + (threadIdx.x >> 6);
    const int lane = threadIdx.x & 63;
    const int wib  = threadIdx.x >> 6;

    // job decode: chunk fastest (adjacent waves share row halo in L2)
    const int chunk = wid & (NCHUNK - 1);
    const int rest  = wid >> 6;
    const int strip = rest % NSTRIP;
    const int batch = rest / NSTRIP;

    const int o0   = chunk * RCHUNK;      // first output row of this job
    const int base = strip * STRIP_OUT;   // first input col of this strip

    int col4 = base + (lane << 2);
    if (col4 > W - 4) col4 = W - 4;       // clamp (strip 4 tail lanes; masked below)

    const float* __restrict__ xb = x + (size_t)batch * H * W;
    const float* __restrict__ yb = y + (size_t)batch * H * W;
    float* __restrict__ ob = out + (size_t)batch * OH * OW;

    const int j4 = base + ((lane - 1) << 2);   // first output col this lane stores
    const bool lane_ok = (lane >= 1) && (lane <= 62) && (j4 <= OW - 4);

    constexpr float inv25 = 1.0f / 25.0f;

    float4 z4 = make_float4(0.f, 0.f, 0.f, 0.f);
    float4 vx = z4, vy = z4, vp = z4;
    float4 cxA = z4, cxB = z4, cyA = z4, cyB = z4;   // rows r-1, r-2 delay regs

    float4* const prw = &pring[wib * 5 * 64 + lane];  // this wave's ring, lane slot
    int u5 = 0;                                       // ring slot counter

    // prefetch row 0 (new rows); old-row prefetch regs start dead
    float4 xn_n, yn_n, xo_n = z4, yo_n = z4;
    {
        int r = o0; if (r > H - 1) r = H - 1;
        const int off = r * W + col4;
        xn_n = *(const float4*)(xb + off);
        yn_n = *(const float4*)(yb + off);
    }

    #pragma unroll 1
    for (int s = 0; s < NSTEP; ++s) {
        const float4 xn = xn_n, yn = yn_n;
        const float4 xo = xo_n, yo = yo_n;

        // issue next iteration's streamed loads NOW (latency hidden under
        // this step's shfl+VALU chain)
        if (s + 1 < NSTEP) {
            int rn = o0 + s + 1; if (rn > H - 1) rn = H - 1;
            const int offn = rn * W + col4;
            xn_n = *(const float4*)(xb + offn);
            yn_n = *(const float4*)(yb + offn);
            if (s + 1 >= 5) {
                int ro = o0 + s - 4; if (ro > H - 1) ro = H - 1;  // R((s+1)-5)
                const int offo = ro * W + col4;
                xo_n = *(const float4*)(xb + offo);
                yo_n = *(const float4*)(yb + offo);
            }
        }

        // vertical running 5-sums: add row R(s), drop row R(s-5)
        if (s >= 5) {
            vx.x += xn.x - xo.x; vx.y += xn.y - xo.y;
            vx.z += xn.z - xo.z; vx.w += xn.w - xo.w;
            vy.x += yn.x - yo.x; vy.y += yn.y - yo.y;
            vy.z += yn.z - yo.z; vy.w += yn.w - yo.w;
        } else {
            vx.x += xn.x; vx.y += xn.y; vx.z += xn.z; vx.w += xn.w;
            vy.x += yn.x; vy.y += yn.y; vy.z += yn.z; vy.w += yn.w;
        }

        // center row R(s-2) from delay regs
        const float4 cx4 = cxB, cy4 = cyB;
        cxB = cxA; cyB = cyA; cxA = xn; cyA = yn;

        if (s >= 4) {
            // horizontal 5-sums at this lane's 4 cols (neighbors via shfl)
            const float vxl0 = shfl_up1(vx.z), vxl1 = shfl_up1(vx.w);
            const float vxr0 = shfl_dn1(vx.x), vxr1 = shfl_dn1(vx.y);
            const float vyl0 = shfl_up1(vy.z), vyl1 = shfl_up1(vy.w);
            const float vyr0 = shfl_dn1(vy.x), vyr1 = shfl_dn1(vy.y);

            const float hx0 = vxl0 + vxl1 + vx.x + vx.y + vx.z;
            const float hx1 = hx0 - vxl0 + vx.w;
            const float hx2 = hx1 - vxl1 + vxr0;
            const float hx3 = hx2 - vx.x + vxr1;
            const float hy0 = vyl0 + vyl1 + vy.x + vy.y + vy.z;
            const float hy1 = hy0 - vyl0 + vy.w;
            const float hy2 = hy1 - vyl1 + vyr0;
            const float hy3 = hy2 - vy.x + vyr1;

            float4 p;
            p.x = (cx4.x - hx0 * inv25) * (cy4.x - hy0 * inv25);
            p.y = (cx4.y - hx1 * inv25) * (cy4.y - hy1 * inv25);
            p.z = (cx4.z - hx2 * inv25) * (cy4.z - hy2 * inv25);
            p.w = (cx4.w - hx3 * inv25) * (cy4.w - hy3 * inv25);

            // vertical running 5-sum of p; 5-deep history lives in LDS
            float4* const pslot = prw + u5 * 64;
            if (s >= 9) {
                const float4 pold = *pslot;      // ds_read_b128 (own wave's row)
                vp.x += p.x - pold.x; vp.y += p.y - pold.y;
                vp.z += p.z - pold.z; vp.w += p.w - pold.w;
            } else {
                vp.x += p.x; vp.y += p.y; vp.z += p.z; vp.w += p.w;
            }
            *pslot = p;                          // ds_write_b128
            if (++u5 == 5) u5 = 0;

            const int i = o0 + s - 8;            // output row
            if (s >= 8 && i < OH) {              // wave-uniform condition
                const float vpl0 = shfl_up1(vp.z), vpl1 = shfl_up1(vp.w);
                const float vpr0 = shfl_dn1(vp.x), vpr1 = shfl_dn1(vp.y);
                const float h0 = vpl0 + vpl1 + vp.x + vp.y + vp.z;
                const float h1 = h0 - vpl0 + vp.w;
                const float h2 = h1 - vpl1 + vpr0;
                const float h3 = h2 - vp.x + vpr1;
                if (lane_ok) {
                    floatx4 o4 = { h0 * inv25, h1 * inv25, h2 * inv25, h3 * inv25 };
                    __builtin_nontemporal_store(o4, (floatx4*)(ob + (size_t)i * OW + j4));
                }
            }
        }
    }
}

extern "C" void kernel_launch(void* const* d_in, const int* in_sizes, int n_in,
                              void* d_out, int out_size, void* d_ws, size_t ws_size,
                              hipStream_t stream) {
    const float* x = (const float*)d_in[0];
    const float* y = (const float*)d_in[1];
    // d_in[2]/d_in[3]: constant conv masks (1/25 box, center impulse) — baked in.
    float* out = (float*)d_out;

    // 16 batch x 5 strips x 64 row-chunks = 5120 wave-jobs = 1280 blocks x 4 waves
    dim3 grid(NBATCH * NSTRIP * NCHUNK / 4);
    dim3 block(256);
    hipLaunchKernelGGL(cov_kernel, grid, block, 0, stream, x, y, out);
}

// Round 6
// 191.112 us; speedup vs baseline: 1.0629x; 1.0252x over previous
//
#include <hip/hip_runtime.h>

// CovarianceLayer: out = boxmean5x5( (center(x)-boxmean5x5(x)) * (center(y)-boxmean5x5(y)) )
// x,y: [16,1,1024,1024] fp32; out: [16,1,1016,1016] fp32.
//
// r4 post-mortem: LDS p-ring + slim state fixed the spills (VGPR 44, occ 47%,
// HBM 36%) but dur only 89->85us. Per-WAVE-STEP throughput is ~1700-1900 cy in
// EVERY version (r0 2.5w/SIMD spilled, r4 5w/SIMD clean) while no pipe exceeds
// ~25% busy and loads are prefetched a full step (~8500cy) ahead. Remaining
// per-step cost is issue overhead the counters can't attribute: 6 wave-uniform
// branches, waitcnt bubbles, ring-counter, delay-reg v_movs, readdressing --
// ~178 VALU instr/step measured (VALUBusy 21% / 120 wave-steps/SIMD).
//
// r5: identical structure+geometry, but the time loop is FLATTENED to
// straight-line code: 9 specialized prologue steps + 15 branch-free steady
// steps (macro-generated). All s-conditions are compile-time; ring slots
// static; delay regs become renames; fmaf fuses (c - h/25). ~80 VALU/step.
// This is r0's full-unroll WITHOUT r0's register rings (the spill source).
// (r5 submission hit an infra failure — container died before compile;
// resubmitted unchanged.)
//
// Valid outputs per 256-col wave strip: 248 cols (lanes 1..62). 5 strips
// cover 1016. Edge lanes' shfl out-of-range returns own value (finite) ->
// garbage only ever flows into masked-off outputs.

#define W 1024
#define H 1024
#define OW 1016
#define OH 1016
#define NBATCH 16
#define NSTRIP 5
#define NCHUNK 64
#define RCHUNK 16
#define NSTEP (RCHUNK + 8)    // 24 input rows per job
#define STRIP_OUT 248

typedef float floatx4 __attribute__((ext_vector_type(4)));

__device__ __forceinline__ float shfl_up1(float v) { return __shfl_up(v, 1, 64); }
__device__ __forceinline__ float shfl_dn1(float v) { return __shfl_down(v, 1, 64); }

__global__ __launch_bounds__(256) void cov_kernel(
    const float* __restrict__ x, const float* __restrict__ y,
    float* __restrict__ out)
{
    // per-wave p-ring: [wave][slot][lane] float4
    __shared__ float4 pring[4 * 5 * 64];

    const int wid  = (blockIdx.x << 2) + (threadIdx.x >> 6);
    const int lane = threadIdx.x & 63;
    const int wib  = threadIdx.x >> 6;

    // job decode: chunk fastest (adjacent waves share row halo in L2)
    const int chunk = wid & (NCHUNK - 1);
    const int rest  = wid >> 6;
    const int strip = rest % NSTRIP;
    const int batch = rest / NSTRIP;

    const int o0   = chunk * RCHUNK;      // first output row of this job
    const int base = strip * STRIP_OUT;   // first input col of this strip

    int col4 = base + (lane << 2);
    if (col4 > W - 4) col4 = W - 4;       // clamp (strip 4 tail lanes; masked below)

    const float* __restrict__ xb = x + (size_t)batch * H * W;
    const float* __restrict__ yb = y + (size_t)batch * H * W;
    float* __restrict__ ob = out + (size_t)batch * OH * OW;

    const int j4 = base + ((lane - 1) << 2);   // first output col this lane stores
    const bool lane_ok = (lane >= 1) && (lane <= 62) && (j4 <= OW - 4);

    constexpr float inv25 = 1.0f / 25.0f;

    const float4 z4 = make_float4(0.f, 0.f, 0.f, 0.f);
    float4 vx = z4, vy = z4, vp = z4;
    float4 cxA = z4, cxB = z4, cyA = z4, cyB = z4;   // rows r-1, r-2 delay regs

    float4* const prw = &pring[wib * 5 * 64 + lane];  // this wave's ring, lane slot

    // prefetch row 0 (new rows); old-row prefetch regs start dead
    float4 xn_n, yn_n, xo_n = z4, yo_n = z4;
    {
        int r = o0; if (r > H - 1) r = H - 1;
        const int off = r * W + col4;
        xn_n = *(const float4*)(xb + off);
        yn_n = *(const float4*)(yb + off);
    }

// One scan step. SRT: runtime step index. Flags (compile-time constants):
// COLDPF: prefetch old row (for step SRT+1's subtract)   [SRT >= 4]
// CSUB  : vertical sums subtract old row                 [SRT >= 5]
// CP    : compute p, write ring                          [SRT >= 4]
// CRD   : read ring, subtract p(SRT-5) from vp           [SRT >= 9]
// SLOT  : ring slot, (SRT-4) % 5, static
// CEMIT : emit output row o0 + SRT - 8                   [SRT >= 8]
#define STEPX(SRT, COLDPF, CSUB, CP, CRD, SLOT, CEMIT) do {                    \
    const float4 xn = xn_n, yn = yn_n;                                         \
    const float4 xo = xo_n, yo = yo_n;                                         \
    { int rn_ = o0 + (SRT) + 1; if (rn_ > H - 1) rn_ = H - 1;                  \
      const size_t ro4_ = (size_t)rn_ * W + col4;                              \
      xn_n = *(const float4*)(xb + ro4_);                                      \
      yn_n = *(const float4*)(yb + ro4_); }                                    \
    if (COLDPF) {                                                              \
      int ro_ = o0 + (SRT) - 4; if (ro_ > H - 1) ro_ = H - 1;                  \
      const size_t rr4_ = (size_t)ro_ * W + col4;                              \
      xo_n = *(const float4*)(xb + rr4_);                                      \
      yo_n = *(const float4*)(yb + rr4_); }                                    \
    if (CSUB) {                                                                \
      vx.x += xn.x - xo.x; vx.y += xn.y - xo.y;                                \
      vx.z += xn.z - xo.z; vx.w += xn.w - xo.w;                                \
      vy.x += yn.x - yo.x; vy.y += yn.y - yo.y;                                \
      vy.z += yn.z - yo.z; vy.w += yn.w - yo.w;                                \
    } else {                                                                   \
      vx.x += xn.x; vx.y += xn.y; vx.z += xn.z; vx.w += xn.w;                  \
      vy.x += yn.x; vy.y += yn.y; vy.z += yn.z; vy.w += yn.w;                  \
    }                                                                          \
    const float4 cx4 = cxB, cy4 = cyB;                                         \
    cxB = cxA; cyB = cyA; cxA = xn; cyA = yn;                                  \
    if (CP) {                                                                  \
      const float vxl0 = shfl_up1(vx.z), vxl1 = shfl_up1(vx.w);                \
      const float vyl0 = shfl_up1(vy.z), vyl1 = shfl_up1(vy.w);                \
      const float vxr0 = shfl_dn1(vx.x), vxr1 = shfl_dn1(vx.y);                \
      const float vyr0 = shfl_dn1(vy.x), vyr1 = shfl_dn1(vy.y);                \
      const float hx0 = vxl0 + vxl1 + vx.x + vx.y + vx.z;                      \
      const float hx1 = hx0 - vxl0 + vx.w;                                     \
      const float hx2 = hx1 - vxl1 + vxr0;                                     \
      const float hx3 = hx2 - vx.x + vxr1;                                     \
      const float hy0 = vyl0 + vyl1 + vy.x + vy.y + vy.z;                      \
      const float hy1 = hy0 - vyl0 + vy.w;                                     \
      const float hy2 = hy1 - vyl1 + vyr0;                                     \
      const float hy3 = hy2 - vy.x + vyr1;                                     \
      float4 p;                                                                \
      p.x = __builtin_fmaf(-inv25, hx0, cx4.x) * __builtin_fmaf(-inv25, hy0, cy4.x); \
      p.y = __builtin_fmaf(-inv25, hx1, cx4.y) * __builtin_fmaf(-inv25, hy1, cy4.y); \
      p.z = __builtin_fmaf(-inv25, hx2, cx4.z) * __builtin_fmaf(-inv25, hy2, cy4.z); \
      p.w = __builtin_fmaf(-inv25, hx3, cx4.w) * __builtin_fmaf(-inv25, hy3, cy4.w); \
      float4* const pslot_ = prw + (SLOT) * 64;                                \
      if (CRD) {                                                               \
        const float4 pold_ = *pslot_;         /* ds_read_b128, own wave row */ \
        vp.x += p.x - pold_.x; vp.y += p.y - pold_.y;                          \
        vp.z += p.z - pold_.z; vp.w += p.w - pold_.w;                          \
      } else {                                                                 \
        vp.x += p.x; vp.y += p.y; vp.z += p.z; vp.w += p.w;                    \
      }                                                                        \
      *pslot_ = p;                            /* ds_write_b128 */              \
      if (CEMIT) {                                                             \
        const int i_ = o0 + (SRT) - 8;                                         \
        const float vpl0 = shfl_up1(vp.z), vpl1 = shfl_up1(vp.w);              \
        const float vpr0 = shfl_dn1(vp.x), vpr1 = shfl_dn1(vp.y);              \
        const float h0 = vpl0 + vpl1 + vp.x + vp.y + vp.z;                     \
        const float h1 = h0 - vpl0 + vp.w;                                     \
        const float h2 = h1 - vpl1 + vpr0;                                     \
        const float h3 = h2 - vp.x + vpr1;                                     \
        if (lane_ok && i_ < OH) {                                              \
          floatx4 o4_ = { h0 * inv25, h1 * inv25, h2 * inv25, h3 * inv25 };    \
          __builtin_nontemporal_store(o4_, (floatx4*)(ob + (size_t)i_ * OW + j4)); \
        }                                                                      \
      }                                                                        \
    }                                                                          \
} while (0)

    // prologue: steps 0..8 (priming; first output row emitted at s=8)
    STEPX(0, false, false, false, false, 0, false);
    STEPX(1, false, false, false, false, 0, false);
    STEPX(2, false, false, false, false, 0, false);
    STEPX(3, false, false, false, false, 0, false);
    STEPX(4, true,  false, true,  false, 0, false);
    STEPX(5, true,  true,  true,  false, 1, false);
    STEPX(6, true,  true,  true,  false, 2, false);
    STEPX(7, true,  true,  true,  false, 3, false);
    STEPX(8, true,  true,  true,  false, 4, true);

    // steady state: steps 9..23, branch-free, static ring slots
    #pragma unroll
    for (int k = 0; k < 3; ++k) {
        const int sb = 9 + 5 * k;
        STEPX(sb + 0, true, true, true, true, 0, true);
        STEPX(sb + 1, true, true, true, true, 1, true);
        STEPX(sb + 2, true, true, true, true, 2, true);
        STEPX(sb + 3, true, true, true, true, 3, true);
        STEPX(sb + 4, true, true, true, true, 4, true);
    }
#undef STEPX
}

extern "C" void kernel_launch(void* const* d_in, const int* in_sizes, int n_in,
                              void* d_out, int out_size, void* d_ws, size_t ws_size,
                              hipStream_t stream) {
    const float* x = (const float*)d_in[0];
    const float* y = (const float*)d_in[1];
    // d_in[2]/d_in[3]: constant conv masks (1/25 box, center impulse) — baked in.
    float* out = (float*)d_out;

    // 16 batch x 5 strips x 64 row-chunks = 5120 wave-jobs = 1280 blocks x 4 waves
    dim3 grid(NBATCH * NSTRIP * NCHUNK / 4);
    dim3 block(256);
    hipLaunchKernelGGL(cov_kernel, grid, block, 0, stream, x, y, out);
}